// Round 24
// baseline (483.981 us; speedup 1.0000x reference)
//
#include <hip/hip_runtime.h>

#define N_NODES 100000
#define N_PAD   100096   // 1564 * 64 -- covers 2-group blocks, guard-free staging
#define N_EDGES 1600000
#define T_STEPS 6
#define FDIM    64
#define SEG     (T_STEPS * N_NODES)
#define C2      0.01f
#define PADF    68   // LDS row stride: 17 quads, 16B-aligned float4 rows
#define RFL __builtin_amdgcn_readfirstlane

// ===== VERBATIM r22 k_build (int2-packed edge data) =====
__global__ __launch_bounds__(256) void k_build(
    const int* __restrict__ src, const int* __restrict__ dst,
    const int* __restrict__ tix, int* __restrict__ head,
    int2* __restrict__ edat)
{
  const int e = blockIdx.x * blockDim.x + threadIdx.x;
  if (e >= N_EDGES) return;
  const int key = tix[e] * N_NODES + dst[e];
  const int prev = atomicExch(&head[key], e);
  edat[e] = make_int2(src[e], prev);
}

// ===== VERBATIM r22 k_sum6 (scalarized 6-chain walk, fused 8B index load) =====
__global__ __launch_bounds__(256) void k_sum6(
    const float* __restrict__ feat, const int2* __restrict__ edat,
    const int* __restrict__ head, float* __restrict__ sums,
    float* __restrict__ cnt)
{
  const int lane = threadIdx.x & 63;
  const int n = blockIdx.x * (blockDim.x >> 6) + (threadIdx.x >> 6);
  if (n >= N_NODES) return;

  int e0 = RFL(head[(size_t)0 * N_NODES + n]);
  int e1 = RFL(head[(size_t)1 * N_NODES + n]);
  int e2 = RFL(head[(size_t)2 * N_NODES + n]);
  int e3 = RFL(head[(size_t)3 * N_NODES + n]);
  int e4 = RFL(head[(size_t)4 * N_NODES + n]);
  int e5 = RFL(head[(size_t)5 * N_NODES + n]);

  float v0 = 0.f, v1 = 0.f, v2 = 0.f, v3 = 0.f, v4 = 0.f, v5 = 0.f;
  int c0 = 0, c1 = 0, c2 = 0, c3 = 0, c4 = 0, c5 = 0;

  while ((e0 >= 0) | (e1 >= 0) | (e2 >= 0) | (e3 >= 0) | (e4 >= 0) | (e5 >= 0)) {
    const int a0 = e0 < 0 ? 0 : e0, a1 = e1 < 0 ? 0 : e1, a2 = e2 < 0 ? 0 : e2;
    const int a3 = e3 < 0 ? 0 : e3, a4 = e4 < 0 ? 0 : e4, a5 = e5 < 0 ? 0 : e5;

    const int2 d0 = edat[a0];
    const int2 d1 = edat[a1];
    const int2 d2 = edat[a2];
    const int2 d3 = edat[a3];
    const int2 d4 = edat[a4];
    const int2 d5 = edat[a5];

    const int s0 = RFL(d0.x), x0 = RFL(d0.y);
    const int s1 = RFL(d1.x), x1 = RFL(d1.y);
    const int s2 = RFL(d2.x), x2 = RFL(d2.y);
    const int s3 = RFL(d3.x), x3 = RFL(d3.y);
    const int s4 = RFL(d4.x), x4 = RFL(d4.y);
    const int s5 = RFL(d5.x), x5 = RFL(d5.y);

    const float f0 = feat[(size_t)s0 * FDIM + lane];
    const float f1 = feat[(size_t)s1 * FDIM + lane];
    const float f2 = feat[(size_t)s2 * FDIM + lane];
    const float f3 = feat[(size_t)s3 * FDIM + lane];
    const float f4 = feat[(size_t)s4 * FDIM + lane];
    const float f5 = feat[(size_t)s5 * FDIM + lane];

    v0 += (e0 >= 0) ? f0 : 0.0f;  c0 += (e0 >= 0);  e0 = (e0 >= 0) ? x0 : -1;
    v1 += (e1 >= 0) ? f1 : 0.0f;  c1 += (e1 >= 0);  e1 = (e1 >= 0) ? x1 : -1;
    v2 += (e2 >= 0) ? f2 : 0.0f;  c2 += (e2 >= 0);  e2 = (e2 >= 0) ? x2 : -1;
    v3 += (e3 >= 0) ? f3 : 0.0f;  c3 += (e3 >= 0);  e3 = (e3 >= 0) ? x3 : -1;
    v4 += (e4 >= 0) ? f4 : 0.0f;  c4 += (e4 >= 0);  e4 = (e4 >= 0) ? x4 : -1;
    v5 += (e5 >= 0) ? f5 : 0.0f;  c5 += (e5 >= 0);  e5 = (e5 >= 0) ? x5 : -1;
  }

  sums[((size_t)0 * N_PAD + n) * FDIM + lane] = v0;
  sums[((size_t)1 * N_PAD + n) * FDIM + lane] = v1;
  sums[((size_t)2 * N_PAD + n) * FDIM + lane] = v2;
  sums[((size_t)3 * N_PAD + n) * FDIM + lane] = v3;
  sums[((size_t)4 * N_PAD + n) * FDIM + lane] = v4;
  sums[((size_t)5 * N_PAD + n) * FDIM + lane] = v5;
  if (lane == 0) {
    cnt[(size_t)0 * N_NODES + n] = (float)c0;
    cnt[(size_t)1 * N_NODES + n] = (float)c1;
    cnt[(size_t)2 * N_NODES + n] = (float)c2;
    cnt[(size_t)3 * N_NODES + n] = (float)c3;
    cnt[(size_t)4 * N_NODES + n] = (float)c4;
    cnt[(size_t)5 * N_NODES + n] = (float)c5;
  }
}

// r22 gemm with TWO independent 64-node groups per 512-thread block.
// Waves 0-3 = 4 j-slices of group 0; waves 4-7 = group 1. Each wave keeps
// the exact r22 per-thread workload (pass A + pass B verbatim) -- this is
// pure co-residency packing: 69.6KB LDS -> 2 blocks/CU -> 16 waves/CU
// (r22: 34.8KB but only ~12 waves/CU resident; the stage-barrier latency
// was exposed). r15's failure halved per-wave work; this doesn't.
// g and jb scalarized via readfirstlane (r7 lesson).
template <int OUTF, int JBLK>
__global__ __launch_bounds__(512) void k_gemm_g2(
    const float* __restrict__ sums, const float* __restrict__ cnt,
    const float* __restrict__ W, const float* __restrict__ bias,
    float* __restrict__ out)
{
  extern __shared__ float lds[];   // [2 groups][2 planes][64*PADF] = 69632 B
  const int tid = threadIdx.x;
  const int lane = tid & 63;
  const int g  = RFL(tid >> 8);                 // group 0/1 (wave-uniform)
  const int jb = RFL((tid >> 6) & 3) * JBLK;    // j-slice (wave-uniform)
  const int gbase = g * (2 * 64 * PADF);

  int n = blockIdx.x * 128 + g * 64 + lane;
  const bool valid = (n < N_NODES);
  if (!valid) n = N_NODES - 1;

  float acc[JBLK];
  #pragma unroll
  for (int j = 0; j < JBLK; ++j) acc[j] = bias[jb + j];

  #pragma unroll 1
  for (int tp = 0; tp < T_STEPS / 2; ++tp) {
    __syncthreads();
    // stage both groups x both planes: 4096 items, 8 per thread
    float4 reg[8];
    #pragma unroll
    for (int it = 0; it < 8; ++it) {
      const int item = tid + it * 512;
      const int q  = item & 15;
      const int u  = (item >> 4) & 63;
      const int r  = item >> 10;        // 0..3
      const int pl = r & 1;
      const int gg = r >> 1;
      reg[it] = *(const float4*)(sums +
          ((size_t)(2 * tp + pl) * N_PAD + blockIdx.x * 128 + gg * 64 + u) * FDIM + q * 4);
    }
    #pragma unroll
    for (int it = 0; it < 8; ++it) {
      const int item = tid + it * 512;
      const int q  = item & 15;
      const int u  = (item >> 4) & 63;
      const int r  = item >> 10;
      const int pl = r & 1;
      const int gg = r >> 1;
      *(float4*)(&lds[gg * (2 * 64 * PADF) + pl * (64 * PADF) + u * PADF + q * 4]) = reg[it];
    }
    __syncthreads();

    #pragma unroll
    for (int pl = 0; pl < 2; ++pl) {
      const int t = 2 * tp + pl;

      // ---- pass A for this t (verbatim r1/r22 rounding) ----
      const float c  = cnt[(size_t)t * N_NODES + n];
      const float rc = 1.0f / fmaxf(c, 1.0f);
      const float4* row = (const float4*)(&lds[gbase + pl * (64 * PADF) + lane * PADF]);
      float ss = 0.0f;
      #pragma unroll
      for (int q = 0; q < FDIM / 4; ++q) {
        float4 v = row[q];
        float m0 = v.x * rc, m1 = v.y * rc, m2 = v.z * rc, m3 = v.w * rc;
        ss += m0 * m0 + m1 * m1 + m2 * m2 + m3 * m3;
      }
      const float norm = 1.0f - C2 * ss;
      const float s = rc / norm;

      // ---- pass B partial for this t, j-slice [jb, jb+JBLK) ----
      #pragma unroll
      for (int q8 = 0; q8 < FDIM / 8; ++q8) {
        const float4 a = row[q8 * 2 + 0];
        const float4 b4 = row[q8 * 2 + 1];
        const float hv[8] = {a.x, a.y, a.z, a.w, b4.x, b4.y, b4.z, b4.w};
        const float* wr = W + ((size_t)t * FDIM + q8 * 8) * OUTF + jb;
        #pragma unroll
        for (int i = 0; i < 8; ++i) {
          const float hs = hv[i] * s;
          #pragma unroll
          for (int j = 0; j < JBLK; ++j)
            acc[j] = fmaf(hs, wr[i * OUTF + j], acc[j]);
        }
      }
    }
  }

  if (valid) {
    float* o = out + (size_t)n * OUTF + jb;
    #pragma unroll
    for (int j = 0; j < JBLK; ++j) o[j] = fmaxf(acc[j], 0.0f);
  }
}

extern "C" void kernel_launch(void* const* d_in, const int* in_sizes, int n_in,
                              void* d_out, int out_size, void* d_ws, size_t ws_size,
                              hipStream_t stream) {
  const float* x  = (const float*)d_in[0];
  const int*  ei  = (const int*)d_in[1];
  const int*  tix = (const int*)d_in[2];
  const float* W1 = (const float*)d_in[3];
  const float* b1 = (const float*)d_in[4];
  const float* W2 = (const float*)d_in[5];
  const float* b2 = (const float*)d_in[6];

  const int* src = ei;
  const int* dst = ei + N_EDGES;

  // Workspace: head[SEG] (2.4MB) | edat[NE] int2 (12.8MB) | sums[6*N_PAD*64]
  //          | cnt[SEG] | h1[N_NODES*64].  head+edat = 15.2MB (256B-multiple)
  // -> sums rows 256B-aligned (r21 lesson). Total ~196.9MB.
  int*   head = (int*)d_ws;
  int2*  edat = (int2*)(head + SEG);
  float* sums = (float*)(edat + N_EDGES);
  float* cnt  = sums + (size_t)T_STEPS * N_PAD * FDIM;
  float* h1   = cnt + SEG;

  const int sum_grid = (N_NODES + 3) / 4;        // k_sum6: 4 waves/block
  const int g2_grid  = (N_NODES + 127) / 128;    // 782 two-group blocks
  constexpr unsigned LDSB = 2u * 2u * 64u * PADF * sizeof(float);  // 69632

  (void)hipFuncSetAttribute((const void*)&k_gemm_g2<64, 16>,
                            hipFuncAttributeMaxDynamicSharedMemorySize, (int)LDSB);
  (void)hipFuncSetAttribute((const void*)&k_gemm_g2<16, 4>,
                            hipFuncAttributeMaxDynamicSharedMemorySize, (int)LDSB);

  hipMemsetAsync(head, 0xFF, (size_t)SEG * sizeof(int), stream);
  k_build<<<(N_EDGES + 255) / 256, 256, 0, stream>>>(src, dst, tix, head, edat);

  // Layer 1
  k_sum6<<<sum_grid, 256, 0, stream>>>(x, edat, head, sums, cnt);
  k_gemm_g2<64, 16><<<g2_grid, 512, LDSB, stream>>>(sums, cnt, W1, b1, h1);

  // Layer 2 (same edge lists; cnt identical but rewritten -- harmless)
  k_sum6<<<sum_grid, 256, 0, stream>>>(h1, edat, head, sums, cnt);
  k_gemm_g2<16, 4><<<g2_grid, 512, LDSB, stream>>>(sums, cnt, W2, b2, (float*)d_out);
}

// Round 25
// 429.106 us; speedup vs baseline: 1.1279x; 1.1279x over previous
//
#include <hip/hip_runtime.h>

#define N_NODES 100000
#define N_PAD   100032   // 1563 * 64 -- padded node count for guard-free staging
#define N_EDGES 1600000
#define T_STEPS 6
#define FDIM    64
#define SEG     (T_STEPS * N_NODES)
#define C2      0.01f
#define PADF    68   // LDS row stride: 17 quads, 16B-aligned float4 rows
#define RFL __builtin_amdgcn_readfirstlane

// ===== VERBATIM r22 k_build (int2-packed edge data) =====
__global__ __launch_bounds__(256) void k_build(
    const int* __restrict__ src, const int* __restrict__ dst,
    const int* __restrict__ tix, int* __restrict__ head,
    int2* __restrict__ edat)
{
  const int e = blockIdx.x * blockDim.x + threadIdx.x;
  if (e >= N_EDGES) return;
  const int key = tix[e] * N_NODES + dst[e];
  const int prev = atomicExch(&head[key], e);
  edat[e] = make_int2(src[e], prev);
}

// ===== VERBATIM r22 k_sum6 (scalarized 6-chain walk, fused 8B index load) =====
__global__ __launch_bounds__(256) void k_sum6(
    const float* __restrict__ feat, const int2* __restrict__ edat,
    const int* __restrict__ head, float* __restrict__ sums,
    float* __restrict__ cnt)
{
  const int lane = threadIdx.x & 63;
  const int n = blockIdx.x * (blockDim.x >> 6) + (threadIdx.x >> 6);
  if (n >= N_NODES) return;

  int e0 = RFL(head[(size_t)0 * N_NODES + n]);
  int e1 = RFL(head[(size_t)1 * N_NODES + n]);
  int e2 = RFL(head[(size_t)2 * N_NODES + n]);
  int e3 = RFL(head[(size_t)3 * N_NODES + n]);
  int e4 = RFL(head[(size_t)4 * N_NODES + n]);
  int e5 = RFL(head[(size_t)5 * N_NODES + n]);

  float v0 = 0.f, v1 = 0.f, v2 = 0.f, v3 = 0.f, v4 = 0.f, v5 = 0.f;
  int c0 = 0, c1 = 0, c2 = 0, c3 = 0, c4 = 0, c5 = 0;

  while ((e0 >= 0) | (e1 >= 0) | (e2 >= 0) | (e3 >= 0) | (e4 >= 0) | (e5 >= 0)) {
    const int a0 = e0 < 0 ? 0 : e0, a1 = e1 < 0 ? 0 : e1, a2 = e2 < 0 ? 0 : e2;
    const int a3 = e3 < 0 ? 0 : e3, a4 = e4 < 0 ? 0 : e4, a5 = e5 < 0 ? 0 : e5;

    const int2 d0 = edat[a0];
    const int2 d1 = edat[a1];
    const int2 d2 = edat[a2];
    const int2 d3 = edat[a3];
    const int2 d4 = edat[a4];
    const int2 d5 = edat[a5];

    const int s0 = RFL(d0.x), x0 = RFL(d0.y);
    const int s1 = RFL(d1.x), x1 = RFL(d1.y);
    const int s2 = RFL(d2.x), x2 = RFL(d2.y);
    const int s3 = RFL(d3.x), x3 = RFL(d3.y);
    const int s4 = RFL(d4.x), x4 = RFL(d4.y);
    const int s5 = RFL(d5.x), x5 = RFL(d5.y);

    const float f0 = feat[(size_t)s0 * FDIM + lane];
    const float f1 = feat[(size_t)s1 * FDIM + lane];
    const float f2 = feat[(size_t)s2 * FDIM + lane];
    const float f3 = feat[(size_t)s3 * FDIM + lane];
    const float f4 = feat[(size_t)s4 * FDIM + lane];
    const float f5 = feat[(size_t)s5 * FDIM + lane];

    v0 += (e0 >= 0) ? f0 : 0.0f;  c0 += (e0 >= 0);  e0 = (e0 >= 0) ? x0 : -1;
    v1 += (e1 >= 0) ? f1 : 0.0f;  c1 += (e1 >= 0);  e1 = (e1 >= 0) ? x1 : -1;
    v2 += (e2 >= 0) ? f2 : 0.0f;  c2 += (e2 >= 0);  e2 = (e2 >= 0) ? x2 : -1;
    v3 += (e3 >= 0) ? f3 : 0.0f;  c3 += (e3 >= 0);  e3 = (e3 >= 0) ? x3 : -1;
    v4 += (e4 >= 0) ? f4 : 0.0f;  c4 += (e4 >= 0);  e4 = (e4 >= 0) ? x4 : -1;
    v5 += (e5 >= 0) ? f5 : 0.0f;  c5 += (e5 >= 0);  e5 = (e5 >= 0) ? x5 : -1;
  }

  sums[((size_t)0 * N_PAD + n) * FDIM + lane] = v0;
  sums[((size_t)1 * N_PAD + n) * FDIM + lane] = v1;
  sums[((size_t)2 * N_PAD + n) * FDIM + lane] = v2;
  sums[((size_t)3 * N_PAD + n) * FDIM + lane] = v3;
  sums[((size_t)4 * N_PAD + n) * FDIM + lane] = v4;
  sums[((size_t)5 * N_PAD + n) * FDIM + lane] = v5;
  if (lane == 0) {
    cnt[(size_t)0 * N_NODES + n] = (float)c0;
    cnt[(size_t)1 * N_NODES + n] = (float)c1;
    cnt[(size_t)2 * N_NODES + n] = (float)c2;
    cnt[(size_t)3 * N_NODES + n] = (float)c3;
    cnt[(size_t)4 * N_NODES + n] = (float)c4;
    cnt[(size_t)5 * N_NODES + n] = (float)c5;
  }
}

// r22 gemm with pass A computed ONCE per block (was 4x redundant across the
// j-slice waves; r23 measured pass A = 15us/dispatch of LDS reads+divides).
// After staging, wave 0 computes s for plane 0 and wave 1 for plane 1 --
// VERBATIM r1/r22 expression tree on the identical LDS rows and cnt loads,
// so s is bit-identical -- stored in sbuf[2][64]; one extra barrier; all 4
// waves then run pass B reading s from sbuf (stride-1, conflict-free).
// Everything else (staging clause, jb scalarization, two-plane rounds,
// static LDS -- r24 showed extern/dynamic LDS costs occupancy + conflicts)
// verbatim r22 -> bit-identical output.
template <int OUTF, int JBLK>
__global__ __launch_bounds__(256) void k_gemm_s(
    const float* __restrict__ sums, const float* __restrict__ cnt,
    const float* __restrict__ W, const float* __restrict__ bias,
    float* __restrict__ out)
{
  __shared__ float lds[2][64 * PADF];   // 2 planes x 17408 B
  __shared__ float sbuf[2][64];         // per-plane scale factors
  const int tid = threadIdx.x;
  const int lane = tid & 63;
  const int wv = tid >> 6;
  const int n0 = blockIdx.x * 64;
  const int jb = RFL(wv) * JBLK;

  int n = n0 + lane;
  const bool valid = (n < N_NODES);
  if (!valid) n = N_NODES - 1;

  float acc[JBLK];
  #pragma unroll
  for (int j = 0; j < JBLK; ++j) acc[j] = bias[jb + j];

  #pragma unroll 1
  for (int tp = 0; tp < T_STEPS / 2; ++tp) {
    __syncthreads();
    float4 reg[8];
    #pragma unroll
    for (int it = 0; it < 8; ++it) {
      const int item = tid + it * 256;
      const int q = item & 15;
      const int u = (item >> 4) & 63;
      const int pl = item >> 10;
      reg[it] = *(const float4*)(sums + ((size_t)(2 * tp + pl) * N_PAD + n0 + u) * FDIM + q * 4);
    }
    #pragma unroll
    for (int it = 0; it < 8; ++it) {
      const int item = tid + it * 256;
      const int q = item & 15;
      const int u = (item >> 4) & 63;
      const int pl = item >> 10;
      *(float4*)(&lds[pl][u * PADF + q * 4]) = reg[it];
    }
    __syncthreads();

    // ---- pass A once per block: wave wv<2 handles plane wv (verbatim) ----
    if (wv < 2) {
      const int t = 2 * tp + wv;
      const float c  = cnt[(size_t)t * N_NODES + n];
      const float rc = 1.0f / fmaxf(c, 1.0f);
      const float4* row = (const float4*)(&lds[wv][lane * PADF]);
      float ss = 0.0f;
      #pragma unroll
      for (int q = 0; q < FDIM / 4; ++q) {
        float4 v = row[q];
        float m0 = v.x * rc, m1 = v.y * rc, m2 = v.z * rc, m3 = v.w * rc;
        ss += m0 * m0 + m1 * m1 + m2 * m2 + m3 * m3;
      }
      const float norm = 1.0f - C2 * ss;
      sbuf[wv][lane] = rc / norm;
    }
    __syncthreads();

    #pragma unroll
    for (int pl = 0; pl < 2; ++pl) {
      const int t = 2 * tp + pl;
      const float s = sbuf[pl][lane];   // bit-identical to per-wave pass A
      const float4* row = (const float4*)(&lds[pl][lane * PADF]);

      // ---- pass B partial for this t, j-slice [jb, jb+JBLK) (verbatim) ----
      #pragma unroll
      for (int q8 = 0; q8 < FDIM / 8; ++q8) {
        const float4 a = row[q8 * 2 + 0];
        const float4 b4 = row[q8 * 2 + 1];
        const float hv[8] = {a.x, a.y, a.z, a.w, b4.x, b4.y, b4.z, b4.w};
        const float* wr = W + ((size_t)t * FDIM + q8 * 8) * OUTF + jb;
        #pragma unroll
        for (int i = 0; i < 8; ++i) {
          const float hs = hv[i] * s;
          #pragma unroll
          for (int j = 0; j < JBLK; ++j)
            acc[j] = fmaf(hs, wr[i * OUTF + j], acc[j]);
        }
      }
    }
  }

  if (valid) {
    float* o = out + (size_t)n * OUTF + jb;
    #pragma unroll
    for (int j = 0; j < JBLK; ++j) o[j] = fmaxf(acc[j], 0.0f);
  }
}

extern "C" void kernel_launch(void* const* d_in, const int* in_sizes, int n_in,
                              void* d_out, int out_size, void* d_ws, size_t ws_size,
                              hipStream_t stream) {
  const float* x  = (const float*)d_in[0];
  const int*  ei  = (const int*)d_in[1];
  const int*  tix = (const int*)d_in[2];
  const float* W1 = (const float*)d_in[3];
  const float* b1 = (const float*)d_in[4];
  const float* W2 = (const float*)d_in[5];
  const float* b2 = (const float*)d_in[6];

  const int* src = ei;
  const int* dst = ei + N_EDGES;

  // Workspace (r22 layout): head[SEG] (2.4MB) | edat[NE] int2 (12.8MB) |
  // sums[6*N_PAD*64] | cnt[SEG] | h1[N_PAD*64]. head+edat = 15.2MB
  // (256B-multiple) -> sums rows 256B-aligned (r21 lesson).
  int*   head = (int*)d_ws;
  int2*  edat = (int2*)(head + SEG);
  float* sums = (float*)(edat + N_EDGES);
  float* cnt  = sums + (size_t)T_STEPS * N_PAD * FDIM;
  float* h1   = cnt + SEG;

  const int sum_grid = (N_NODES + 3) / 4;        // k_sum6: 4 waves/block
  const int ngrp     = (N_NODES + 63) / 64;      // 1563 64-node groups

  hipMemsetAsync(head, 0xFF, (size_t)SEG * sizeof(int), stream);
  k_build<<<(N_EDGES + 255) / 256, 256, 0, stream>>>(src, dst, tix, head, edat);

  // Layer 1
  k_sum6<<<sum_grid, 256, 0, stream>>>(x, edat, head, sums, cnt);
  k_gemm_s<64, 16><<<ngrp, 256, 0, stream>>>(sums, cnt, W1, b1, h1);

  // Layer 2 (same edge lists; cnt identical but rewritten -- harmless)
  k_sum6<<<sum_grid, 256, 0, stream>>>(h1, edat, head, sums, cnt);
  k_gemm_s<16, 4><<<ngrp, 256, 0, stream>>>(sums, cnt, W2, b2, (float*)d_out);
}

// Round 26
// 425.388 us; speedup vs baseline: 1.1377x; 1.0087x over previous
//
#include <hip/hip_runtime.h>

#define N_NODES 100000
#define N_PAD   100032   // 1563 * 64 -- padded node count for guard-free staging
#define N_EDGES 1600000
#define T_STEPS 6
#define FDIM    64
#define SEG     (T_STEPS * N_NODES)
#define C2      0.01f
#define PADF    68   // LDS row stride: 17 quads (272B); plane = 64*272B = 17408B
#define RFL __builtin_amdgcn_readfirstlane

// ===== VERBATIM r22 k_build (int2-packed edge data) =====
__global__ __launch_bounds__(256) void k_build(
    const int* __restrict__ src, const int* __restrict__ dst,
    const int* __restrict__ tix, int* __restrict__ head,
    int2* __restrict__ edat)
{
  const int e = blockIdx.x * blockDim.x + threadIdx.x;
  if (e >= N_EDGES) return;
  const int key = tix[e] * N_NODES + dst[e];
  const int prev = atomicExch(&head[key], e);
  edat[e] = make_int2(src[e], prev);
}

// ===== VERBATIM r22 k_sum6 (scalarized 6-chain walk, fused 8B index load) =====
__global__ __launch_bounds__(256) void k_sum6(
    const float* __restrict__ feat, const int2* __restrict__ edat,
    const int* __restrict__ head, float* __restrict__ sums,
    float* __restrict__ cnt)
{
  const int lane = threadIdx.x & 63;
  const int n = blockIdx.x * (blockDim.x >> 6) + (threadIdx.x >> 6);
  if (n >= N_NODES) return;

  int e0 = RFL(head[(size_t)0 * N_NODES + n]);
  int e1 = RFL(head[(size_t)1 * N_NODES + n]);
  int e2 = RFL(head[(size_t)2 * N_NODES + n]);
  int e3 = RFL(head[(size_t)3 * N_NODES + n]);
  int e4 = RFL(head[(size_t)4 * N_NODES + n]);
  int e5 = RFL(head[(size_t)5 * N_NODES + n]);

  float v0 = 0.f, v1 = 0.f, v2 = 0.f, v3 = 0.f, v4 = 0.f, v5 = 0.f;
  int c0 = 0, c1 = 0, c2 = 0, c3 = 0, c4 = 0, c5 = 0;

  while ((e0 >= 0) | (e1 >= 0) | (e2 >= 0) | (e3 >= 0) | (e4 >= 0) | (e5 >= 0)) {
    const int a0 = e0 < 0 ? 0 : e0, a1 = e1 < 0 ? 0 : e1, a2 = e2 < 0 ? 0 : e2;
    const int a3 = e3 < 0 ? 0 : e3, a4 = e4 < 0 ? 0 : e4, a5 = e5 < 0 ? 0 : e5;

    const int2 d0 = edat[a0];
    const int2 d1 = edat[a1];
    const int2 d2 = edat[a2];
    const int2 d3 = edat[a3];
    const int2 d4 = edat[a4];
    const int2 d5 = edat[a5];

    const int s0 = RFL(d0.x), x0 = RFL(d0.y);
    const int s1 = RFL(d1.x), x1 = RFL(d1.y);
    const int s2 = RFL(d2.x), x2 = RFL(d2.y);
    const int s3 = RFL(d3.x), x3 = RFL(d3.y);
    const int s4 = RFL(d4.x), x4 = RFL(d4.y);
    const int s5 = RFL(d5.x), x5 = RFL(d5.y);

    const float f0 = feat[(size_t)s0 * FDIM + lane];
    const float f1 = feat[(size_t)s1 * FDIM + lane];
    const float f2 = feat[(size_t)s2 * FDIM + lane];
    const float f3 = feat[(size_t)s3 * FDIM + lane];
    const float f4 = feat[(size_t)s4 * FDIM + lane];
    const float f5 = feat[(size_t)s5 * FDIM + lane];

    v0 += (e0 >= 0) ? f0 : 0.0f;  c0 += (e0 >= 0);  e0 = (e0 >= 0) ? x0 : -1;
    v1 += (e1 >= 0) ? f1 : 0.0f;  c1 += (e1 >= 0);  e1 = (e1 >= 0) ? x1 : -1;
    v2 += (e2 >= 0) ? f2 : 0.0f;  c2 += (e2 >= 0);  e2 = (e2 >= 0) ? x2 : -1;
    v3 += (e3 >= 0) ? f3 : 0.0f;  c3 += (e3 >= 0);  e3 = (e3 >= 0) ? x3 : -1;
    v4 += (e4 >= 0) ? f4 : 0.0f;  c4 += (e4 >= 0);  e4 = (e4 >= 0) ? x4 : -1;
    v5 += (e5 >= 0) ? f5 : 0.0f;  c5 += (e5 >= 0);  e5 = (e5 >= 0) ? x5 : -1;
  }

  sums[((size_t)0 * N_PAD + n) * FDIM + lane] = v0;
  sums[((size_t)1 * N_PAD + n) * FDIM + lane] = v1;
  sums[((size_t)2 * N_PAD + n) * FDIM + lane] = v2;
  sums[((size_t)3 * N_PAD + n) * FDIM + lane] = v3;
  sums[((size_t)4 * N_PAD + n) * FDIM + lane] = v4;
  sums[((size_t)5 * N_PAD + n) * FDIM + lane] = v5;
  if (lane == 0) {
    cnt[(size_t)0 * N_NODES + n] = (float)c0;
    cnt[(size_t)1 * N_NODES + n] = (float)c1;
    cnt[(size_t)2 * N_NODES + n] = (float)c2;
    cnt[(size_t)3 * N_NODES + n] = (float)c3;
    cnt[(size_t)4 * N_NODES + n] = (float)c4;
    cnt[(size_t)5 * N_NODES + n] = (float)c5;
  }
}

// Direct global->LDS (no VGPR round trip). Lane-linear dest (m104): wave
// writes 1KB at uniform base; lane l's 16B comes from its own global addr.
__device__ __forceinline__ void gl16(const float* g, float* l) {
  __builtin_amdgcn_global_load_lds(
      (const __attribute__((address_space(1))) void*)g,
      (__attribute__((address_space(3))) void*)l, 16, 0, 0);
}

// r22 gemm with global_load_lds SOFTWARE PIPELINE. r14/r19 proved reg-staged
// pipelining explodes VGPR (76/405us, 216/1143us); global_load_lds stages
// with ZERO registers, so next round's planes are issued into the other
// buffer before compute, and the single end-of-round barrier's vmcnt(0)
// drain lands AFTER ~4400cy of fma -- the L3 stage latency r22 exposed 3x
// per block is now hidden. LDS placement is byte-identical to r22's staging
// (PADF=68 row = 17 quads; chunk unit p -> u=p/17, q=p%17; q==16 is the pad
// quad, filled with junk, never read). Pass A (per-wave) + pass B are
// VERBATIM r22 expression trees -> bit-identical output.
template <int OUTF, int JBLK>
__global__ __launch_bounds__(256) void k_gemm_gl(
    const float* __restrict__ sums, const float* __restrict__ cnt,
    const float* __restrict__ W, const float* __restrict__ bias,
    float* __restrict__ out)
{
  __shared__ float lds[2][64 * PADF];   // 2 buffers x 17408 B (2 planes each? no: 1 buffer = 2 planes)
  // NOTE: buffer = 2 planes of 64 rows -> 2*17408 = 34816B total, same as r22:
  // lds[b] holds ONE round's pair? Layout: buffer b occupies lds[b] (64*PADF
  // floats = ONE plane). We need 2 planes per round x 2 buffers = 4 planes.
  // Instead: treat lds as flat 2 rounds x 2 planes? LDS budget: keep r22's
  // 34816B -> 2 planes total -> pipeline at PLANE granularity (6 rounds of 1
  // plane, prefetch plane t+1 while computing plane t).
  const int tid = threadIdx.x;
  const int lane = tid & 63;
  const int wv = RFL(tid >> 6);
  const int n0 = blockIdx.x * 64;
  const int jb = wv * JBLK;

  int n = n0 + lane;
  const bool valid = (n < N_NODES);
  if (!valid) n = N_NODES - 1;

  float acc[JBLK];
  #pragma unroll
  for (int j = 0; j < JBLK; ++j) acc[j] = bias[jb + j];

  // stage plane T into lds[B]: 17 chunks of 1KB, wave wv takes chunks wv,wv+4,...
  #define STAGE_PL(B, T)                                                      \
    for (int c = wv; c < 17; c += 4) {                                        \
      const int p  = c * 64 + lane;        /* 16B unit within plane */        \
      const int u  = p / 17;               /* row 0..63 */                    \
      const int qq = (p % 17) & 15;        /* pad quad 16 -> re-read quad 0 */\
      gl16(sums + ((size_t)(T) * N_PAD + n0 + u) * FDIM + qq * 4,             \
           &lds[B][0] + c * 256);                                             \
    }

  STAGE_PL(0, 0);
  __syncthreads();

  #pragma unroll 1
  for (int t = 0; t < T_STEPS; ++t) {
    const float* row4 = &lds[t & 1][lane * PADF];
    // issue next plane's loads into the other buffer (consumed last round,
    // freed by the barrier we just passed); zero VGPR cost.
    if (t + 1 < T_STEPS) { STAGE_PL((t + 1) & 1, t + 1); }

    // ---- pass A for this t (verbatim r1/r22 rounding, per-wave) ----
    const float c  = cnt[(size_t)t * N_NODES + n];
    const float rc = 1.0f / fmaxf(c, 1.0f);
    const float4* row = (const float4*)row4;
    float ss = 0.0f;
    #pragma unroll
    for (int q = 0; q < FDIM / 4; ++q) {
      float4 v = row[q];
      float m0 = v.x * rc, m1 = v.y * rc, m2 = v.z * rc, m3 = v.w * rc;
      ss += m0 * m0 + m1 * m1 + m2 * m2 + m3 * m3;
    }
    const float norm = 1.0f - C2 * ss;
    const float s = rc / norm;

    // ---- pass B partial for this t, j-slice [jb, jb+JBLK) (verbatim) ----
    #pragma unroll
    for (int q8 = 0; q8 < FDIM / 8; ++q8) {
      const float4 a = row[q8 * 2 + 0];
      const float4 b4 = row[q8 * 2 + 1];
      const float hv[8] = {a.x, a.y, a.z, a.w, b4.x, b4.y, b4.z, b4.w};
      const float* wr = W + ((size_t)t * FDIM + q8 * 8) * OUTF + jb;
      #pragma unroll
      for (int i = 0; i < 8; ++i) {
        const float hs = hv[i] * s;
        #pragma unroll
        for (int j = 0; j < JBLK; ++j)
          acc[j] = fmaf(hs, wr[i * OUTF + j], acc[j]);
      }
    }

    __syncthreads();   // single barrier: drains prefetch vmcnt AFTER compute
  }
  #undef STAGE_PL

  if (valid) {
    float* o = out + (size_t)n * OUTF + jb;
    #pragma unroll
    for (int j = 0; j < JBLK; ++j) o[j] = fmaxf(acc[j], 0.0f);
  }
}

extern "C" void kernel_launch(void* const* d_in, const int* in_sizes, int n_in,
                              void* d_out, int out_size, void* d_ws, size_t ws_size,
                              hipStream_t stream) {
  const float* x  = (const float*)d_in[0];
  const int*  ei  = (const int*)d_in[1];
  const int*  tix = (const int*)d_in[2];
  const float* W1 = (const float*)d_in[3];
  const float* b1 = (const float*)d_in[4];
  const float* W2 = (const float*)d_in[5];
  const float* b2 = (const float*)d_in[6];

  const int* src = ei;
  const int* dst = ei + N_EDGES;

  // Workspace (r22 layout): head[SEG] (2.4MB) | edat[NE] int2 (12.8MB) |
  // sums[6*N_PAD*64] | cnt[SEG] | h1[N_PAD*64]. head+edat = 15.2MB
  // (256B-multiple) -> sums rows 256B-aligned (r21 lesson).
  int*   head = (int*)d_ws;
  int2*  edat = (int2*)(head + SEG);
  float* sums = (float*)(edat + N_EDGES);
  float* cnt  = sums + (size_t)T_STEPS * N_PAD * FDIM;
  float* h1   = cnt + SEG;

  const int sum_grid = (N_NODES + 3) / 4;        // k_sum6: 4 waves/block
  const int ngrp     = (N_NODES + 63) / 64;      // 1563 64-node groups

  hipMemsetAsync(head, 0xFF, (size_t)SEG * sizeof(int), stream);
  k_build<<<(N_EDGES + 255) / 256, 256, 0, stream>>>(src, dst, tix, head, edat);

  // Layer 1
  k_sum6<<<sum_grid, 256, 0, stream>>>(x, edat, head, sums, cnt);
  k_gemm_gl<64, 16><<<ngrp, 256, 0, stream>>>(sums, cnt, W1, b1, h1);

  // Layer 2 (same edge lists; cnt identical but rewritten -- harmless)
  k_sum6<<<sum_grid, 256, 0, stream>>>(h1, edat, head, sums, cnt);
  k_gemm_gl<16, 4><<<ngrp, 256, 0, stream>>>(sums, cnt, W2, b2, (float*)d_out);
}

// Round 27
// 420.274 us; speedup vs baseline: 1.1516x; 1.0122x over previous
//
#include <hip/hip_runtime.h>

#define N_NODES 100000
#define N_PAD   100032   // 1563 * 64 -- padded node count for guard-free staging
#define N_EDGES 1600000
#define T_STEPS 6
#define FDIM    64
#define SEG     (T_STEPS * N_NODES)
#define C2      0.01f
#define PADF    68   // LDS row stride: 17 quads (272B); plane = 64*272B = 17408B
#define RFL __builtin_amdgcn_readfirstlane

// ===== VERBATIM r22 k_build (int2-packed edge data) =====
__global__ __launch_bounds__(256) void k_build(
    const int* __restrict__ src, const int* __restrict__ dst,
    const int* __restrict__ tix, int* __restrict__ head,
    int2* __restrict__ edat)
{
  const int e = blockIdx.x * blockDim.x + threadIdx.x;
  if (e >= N_EDGES) return;
  const int key = tix[e] * N_NODES + dst[e];
  const int prev = atomicExch(&head[key], e);
  edat[e] = make_int2(src[e], prev);
}

// r22 k_sum6 walk (verbatim) + FUSED pass A + pre-scale. After the walk the
// wave holds all 6x64 raw sums in registers: stash to wave-private LDS,
// lanes 0-5 run the VERBATIM r1 pass A (sequential float4-chunk ss chain --
// identical bits in, identical expression tree; this exact expression scored
// absmax 128 in 6 different kernel contexts r12-r26), shuffle-broadcast s,
// store v*s. v*s here is bit-identical to the gemm's old hs = hv[i]*s (same
// operands, one f32 mul) -> downstream pass B rounding untouched, and the
// gemm loses pass A + divide + all cnt traffic.
__global__ __launch_bounds__(256) void k_sum6s(
    const float* __restrict__ feat, const int2* __restrict__ edat,
    const int* __restrict__ head, float* __restrict__ hsums)
{
  __shared__ float scr[4][T_STEPS * 64];   // 6KB: wave-private sum stash
  const int lane = threadIdx.x & 63;
  const int w = threadIdx.x >> 6;
  const int n = blockIdx.x * (blockDim.x >> 6) + w;
  if (n >= N_NODES) return;

  int e0 = RFL(head[(size_t)0 * N_NODES + n]);
  int e1 = RFL(head[(size_t)1 * N_NODES + n]);
  int e2 = RFL(head[(size_t)2 * N_NODES + n]);
  int e3 = RFL(head[(size_t)3 * N_NODES + n]);
  int e4 = RFL(head[(size_t)4 * N_NODES + n]);
  int e5 = RFL(head[(size_t)5 * N_NODES + n]);

  float v0 = 0.f, v1 = 0.f, v2 = 0.f, v3 = 0.f, v4 = 0.f, v5 = 0.f;
  int c0 = 0, c1 = 0, c2 = 0, c3 = 0, c4 = 0, c5 = 0;

  while ((e0 >= 0) | (e1 >= 0) | (e2 >= 0) | (e3 >= 0) | (e4 >= 0) | (e5 >= 0)) {
    const int a0 = e0 < 0 ? 0 : e0, a1 = e1 < 0 ? 0 : e1, a2 = e2 < 0 ? 0 : e2;
    const int a3 = e3 < 0 ? 0 : e3, a4 = e4 < 0 ? 0 : e4, a5 = e5 < 0 ? 0 : e5;

    const int2 d0 = edat[a0];
    const int2 d1 = edat[a1];
    const int2 d2 = edat[a2];
    const int2 d3 = edat[a3];
    const int2 d4 = edat[a4];
    const int2 d5 = edat[a5];

    const int s0 = RFL(d0.x), x0 = RFL(d0.y);
    const int s1 = RFL(d1.x), x1 = RFL(d1.y);
    const int s2 = RFL(d2.x), x2 = RFL(d2.y);
    const int s3 = RFL(d3.x), x3 = RFL(d3.y);
    const int s4 = RFL(d4.x), x4 = RFL(d4.y);
    const int s5 = RFL(d5.x), x5 = RFL(d5.y);

    const float f0 = feat[(size_t)s0 * FDIM + lane];
    const float f1 = feat[(size_t)s1 * FDIM + lane];
    const float f2 = feat[(size_t)s2 * FDIM + lane];
    const float f3 = feat[(size_t)s3 * FDIM + lane];
    const float f4 = feat[(size_t)s4 * FDIM + lane];
    const float f5 = feat[(size_t)s5 * FDIM + lane];

    v0 += (e0 >= 0) ? f0 : 0.0f;  c0 += (e0 >= 0);  e0 = (e0 >= 0) ? x0 : -1;
    v1 += (e1 >= 0) ? f1 : 0.0f;  c1 += (e1 >= 0);  e1 = (e1 >= 0) ? x1 : -1;
    v2 += (e2 >= 0) ? f2 : 0.0f;  c2 += (e2 >= 0);  e2 = (e2 >= 0) ? x2 : -1;
    v3 += (e3 >= 0) ? f3 : 0.0f;  c3 += (e3 >= 0);  e3 = (e3 >= 0) ? x3 : -1;
    v4 += (e4 >= 0) ? f4 : 0.0f;  c4 += (e4 >= 0);  e4 = (e4 >= 0) ? x4 : -1;
    v5 += (e5 >= 0) ? f5 : 0.0f;  c5 += (e5 >= 0);  e5 = (e5 >= 0) ? x5 : -1;
  }

  // stash raw sums (wave-private; compiler inserts the lgkmcnt before reads)
  scr[w][0 * 64 + lane] = v0;
  scr[w][1 * 64 + lane] = v1;
  scr[w][2 * 64 + lane] = v2;
  scr[w][3 * 64 + lane] = v3;
  scr[w][4 * 64 + lane] = v4;
  scr[w][5 * 64 + lane] = v5;

  // ---- pass A, verbatim r1 expression tree, lane t handles plane t ----
  float sv = 0.0f;
  if (lane < T_STEPS) {
    const int ci = (lane == 0) ? c0 : (lane == 1) ? c1 : (lane == 2) ? c2
                 : (lane == 3) ? c3 : (lane == 4) ? c4 : c5;
    const float c  = (float)ci;
    const float rc = 1.0f / fmaxf(c, 1.0f);
    const float4* row = (const float4*)(&scr[w][lane * 64]);
    float ss = 0.0f;
    #pragma unroll
    for (int q = 0; q < FDIM / 4; ++q) {
      float4 v = row[q];
      float m0 = v.x * rc, m1 = v.y * rc, m2 = v.z * rc, m3 = v.w * rc;
      ss += m0 * m0 + m1 * m1 + m2 * m2 + m3 * m3;
    }
    const float norm = 1.0f - C2 * ss;
    sv = rc / norm;
  }
  const float sc0 = __shfl(sv, 0, 64);
  const float sc1 = __shfl(sv, 1, 64);
  const float sc2 = __shfl(sv, 2, 64);
  const float sc3 = __shfl(sv, 3, 64);
  const float sc4 = __shfl(sv, 4, 64);
  const float sc5 = __shfl(sv, 5, 64);

  // pre-scaled store: v*s == the gemm's old hs = hv[i]*s, bit-identical
  hsums[((size_t)0 * N_PAD + n) * FDIM + lane] = v0 * sc0;
  hsums[((size_t)1 * N_PAD + n) * FDIM + lane] = v1 * sc1;
  hsums[((size_t)2 * N_PAD + n) * FDIM + lane] = v2 * sc2;
  hsums[((size_t)3 * N_PAD + n) * FDIM + lane] = v3 * sc3;
  hsums[((size_t)4 * N_PAD + n) * FDIM + lane] = v4 * sc4;
  hsums[((size_t)5 * N_PAD + n) * FDIM + lane] = v5 * sc5;
}

// Direct global->LDS (no VGPR round trip). Lane-linear dest: wave writes
// 1KB at uniform base; lane l's 16B comes from its own global addr.
__device__ __forceinline__ void gl16(const float* g, float* l) {
  __builtin_amdgcn_global_load_lds(
      (const __attribute__((address_space(1))) void*)g,
      (__attribute__((address_space(3))) void*)l, 16, 0, 0);
}

// r26 pipelined gemm, pass-B ONLY (hsums arrives pre-scaled): per round,
// issue next plane's global_load_lds into the other buffer (zero VGPR),
// run the fma block, ONE barrier. acc = fmaf(hv[i], wr, acc) where hv[i]
// is bit-identical to r22's hs -> output unchanged. No cnt, no divide,
// LDS reads per plane halve.
template <int OUTF, int JBLK>
__global__ __launch_bounds__(256) void k_gemm_pb(
    const float* __restrict__ hsums, const float* __restrict__ W,
    const float* __restrict__ bias, float* __restrict__ out)
{
  __shared__ float lds[2][64 * PADF];   // 2 plane buffers x 17408 B
  const int tid = threadIdx.x;
  const int lane = tid & 63;
  const int wv = RFL(tid >> 6);
  const int n0 = blockIdx.x * 64;
  const int jb = wv * JBLK;

  int n = n0 + lane;
  const bool valid = (n < N_NODES);
  if (!valid) n = N_NODES - 1;

  float acc[JBLK];
  #pragma unroll
  for (int j = 0; j < JBLK; ++j) acc[j] = bias[jb + j];

  // stage plane T into lds[B]: 17 chunks of 1KB, wave wv takes chunks wv,wv+4,...
  // byte p*16 = u*272 + (p%17)*16; pad quad (q==16) gets junk, never read.
  #define STAGE_PL(B, T)                                                      \
    for (int c = wv; c < 17; c += 4) {                                        \
      const int p  = c * 64 + lane;                                           \
      const int u  = p / 17;                                                  \
      const int qq = (p % 17) & 15;                                           \
      gl16(hsums + ((size_t)(T) * N_PAD + n0 + u) * FDIM + qq * 4,            \
           &lds[B][0] + c * 256);                                             \
    }

  STAGE_PL(0, 0);
  __syncthreads();

  #pragma unroll 1
  for (int t = 0; t < T_STEPS; ++t) {
    const float4* row = (const float4*)(&lds[t & 1][lane * PADF]);
    if (t + 1 < T_STEPS) { STAGE_PL((t + 1) & 1, t + 1); }

    #pragma unroll
    for (int q8 = 0; q8 < FDIM / 8; ++q8) {
      const float4 a = row[q8 * 2 + 0];
      const float4 b4 = row[q8 * 2 + 1];
      const float hv[8] = {a.x, a.y, a.z, a.w, b4.x, b4.y, b4.z, b4.w};
      const float* wr = W + ((size_t)t * FDIM + q8 * 8) * OUTF + jb;
      #pragma unroll
      for (int i = 0; i < 8; ++i) {
        #pragma unroll
        for (int j = 0; j < JBLK; ++j)
          acc[j] = fmaf(hv[i], wr[i * OUTF + j], acc[j]);
      }
    }

    __syncthreads();   // drains prefetch vmcnt AFTER the fma block
  }
  #undef STAGE_PL

  if (valid) {
    float* o = out + (size_t)n * OUTF + jb;
    #pragma unroll
    for (int j = 0; j < JBLK; ++j) o[j] = fmaxf(acc[j], 0.0f);
  }
}

extern "C" void kernel_launch(void* const* d_in, const int* in_sizes, int n_in,
                              void* d_out, int out_size, void* d_ws, size_t ws_size,
                              hipStream_t stream) {
  const float* x  = (const float*)d_in[0];
  const int*  ei  = (const int*)d_in[1];
  const int*  tix = (const int*)d_in[2];
  const float* W1 = (const float*)d_in[3];
  const float* b1 = (const float*)d_in[4];
  const float* W2 = (const float*)d_in[5];
  const float* b2 = (const float*)d_in[6];

  const int* src = ei;
  const int* dst = ei + N_EDGES;

  // Workspace: head[SEG] (2.4MB) | edat[NE] int2 (12.8MB) | hsums[6*N_PAD*64]
  //          | h1[N_PAD*64]. head+edat = 15.2MB (256B-multiple) -> hsums rows
  // 256B-aligned (r21 lesson). cnt array no longer needed.
  int*   head  = (int*)d_ws;
  int2*  edat  = (int2*)(head + SEG);
  float* hsums = (float*)(edat + N_EDGES);
  float* h1    = hsums + (size_t)T_STEPS * N_PAD * FDIM;

  const int sum_grid = (N_NODES + 3) / 4;        // k_sum6s: 4 waves/block
  const int ngrp     = (N_NODES + 63) / 64;      // 1563 64-node groups

  hipMemsetAsync(head, 0xFF, (size_t)SEG * sizeof(int), stream);
  k_build<<<(N_EDGES + 255) / 256, 256, 0, stream>>>(src, dst, tix, head, edat);

  // Layer 1
  k_sum6s<<<sum_grid, 256, 0, stream>>>(x, edat, head, hsums);
  k_gemm_pb<64, 16><<<ngrp, 256, 0, stream>>>(hsums, W1, b1, h1);

  // Layer 2 (same edge lists)
  k_sum6s<<<sum_grid, 256, 0, stream>>>(h1, edat, head, hsums);
  k_gemm_pb<16, 4><<<ngrp, 256, 0, stream>>>(hsums, W2, b2, (float*)d_out);
}